// Round 2
// baseline (859.867 us; speedup 1.0000x reference)
//
#include <hip/hip_runtime.h>
#include <stdint.h>

#define N_NODES 50000
#define N_EDGES 800000

typedef __bf16 bf16x8 __attribute__((ext_vector_type(8)));
typedef float f32x4 __attribute__((ext_vector_type(4)));

__device__ __forceinline__ unsigned short f2bf(float f) {
  union { float f; unsigned int i; } x; x.f = f;
  unsigned int i = x.i;
  unsigned int r = (i + 0x7fffu + ((i >> 16) & 1u)) >> 16;  // round-nearest-even
  return (unsigned short)r;
}

// ---------------------------------------------------------------------------
// Weight transpose+convert: W f32 [k=128][n=128] -> Wt bf16 [n][k] so MFMA
// B-fragments are contiguous ds_read_b128. 8 matrices packed at Wt+mat*16384.
// ---------------------------------------------------------------------------
struct Ptr8 { const float* p[8]; };

__global__ __launch_bounds__(256) void transpose_w(Ptr8 ws, unsigned short* wt) {
  int mat = blockIdx.x;
  const float* W = ws.p[mat];
  unsigned short* out = wt + mat * 16384;
  for (int it = 0; it < 64; ++it) {
    int idx = it * 256 + threadIdx.x;
    int n = idx >> 7, k = idx & 127;
    out[n * 128 + k] = f2bf(W[k * 128 + n]);  // writes coalesced, reads L2-resident
  }
}

// ---------------------------------------------------------------------------
// CSR build: zero, histogram over dst, 1-block scan, scatter (stores {e,src})
// ---------------------------------------------------------------------------
__global__ void zero_kernel(int* cnt, int* cursor) {
  int i = blockIdx.x * blockDim.x + threadIdx.x;
  if (i < N_NODES) { cnt[i] = 0; cursor[i] = 0; }
}

__global__ void hist_kernel(const int* __restrict__ dst, int* __restrict__ cnt) {
  int e = blockIdx.x * blockDim.x + threadIdx.x;
  if (e < N_EDGES) atomicAdd(&cnt[dst[e]], 1);
}

__global__ __launch_bounds__(1024) void scan_kernel(const int* __restrict__ cnt, int* __restrict__ rs) {
  const int n = N_NODES, per = 49;  // ceil(50000/1024)
  int t = threadIdx.x;
  int lo = t * per; int hi = lo + per;
  if (lo > n) lo = n;
  if (hi > n) hi = n;
  int s = 0;
  for (int i = lo; i < hi; ++i) s += cnt[i];
  int lane = t & 63, wv = t >> 6;
  int v = s;
  #pragma unroll
  for (int off = 1; off < 64; off <<= 1) {
    int u = __shfl_up(v, off, 64);
    if (lane >= off) v += u;
  }
  __shared__ int wsum[16], woff[16];
  if (lane == 63) wsum[wv] = v;
  __syncthreads();
  if (t == 0) { int a = 0; for (int w = 0; w < 16; ++w) { woff[w] = a; a += wsum[w]; } }
  __syncthreads();
  int run = woff[wv] + (v - s);  // exclusive prefix for this thread
  if (t == 0) rs[0] = 0;
  for (int i = lo; i < hi; ++i) { run += cnt[i]; rs[i + 1] = run; }
}

__global__ void scatter_kernel(const int* __restrict__ src, const int* __restrict__ dst,
                               const int* __restrict__ rs, int* __restrict__ cursor,
                               int2* __restrict__ eidx2) {
  int e = blockIdx.x * blockDim.x + threadIdx.x;
  if (e < N_EDGES) {
    int d = dst[e];
    int pos = atomicAdd(&cursor[d], 1);
    eidx2[rs[d] + pos] = make_int2(e, src[e]);
  }
}

// ---------------------------------------------------------------------------
// Node GEMM: out = X @ W + b. X either f32 (layer 0) or bf16 (h, layer 1),
// converted to bf16 in LDS staging. W pre-transposed bf16 [n][k]. 4 weight
// mats via blockIdx.y. 128x128 tile, 4 waves 2x2, XOR-swizzled LDS. f32 out.
// ---------------------------------------------------------------------------
struct GemmArgs {
  const float* Xf;              // layer-0 input (f32) or null
  const unsigned short* Xh;     // layer-1 input (bf16) or null
  const unsigned short* Wt;     // 4 transposed bf16 mats packed, [n][k]
  const float* b0; const float* b1; const float* b2; const float* b3;
  float* o0; float* o1; float* o2; float* o3;
  int M;
};

template<bool XF32>
__global__ __launch_bounds__(256) void node_gemm(GemmArgs ga) {
  __shared__ alignas(16) unsigned short At[128 * 128];
  __shared__ alignas(16) unsigned short Bt[128 * 128];
  int which = blockIdx.y;
  const unsigned short* Wt = ga.Wt + which * 16384;
  int m0 = blockIdx.x * 128;

  // stage A (x tile, rows clamped; f32->bf16 convert) and B (Wt copy),
  // 8-elem (16B bf16) chunks with XOR swizzle on the 8-elem slot index
  #pragma unroll
  for (int it = 0; it < 8; ++it) {
    int c = it * 256 + threadIdx.x;        // chunk id, 0..2047
    int row = c >> 4, slot = c & 15;
    int dsl = slot ^ (row & 7);
    int grow = m0 + row; if (grow >= ga.M) grow = ga.M - 1;
    alignas(16) unsigned short tmp[8];
    if (XF32) {
      const float* xp = ga.Xf + (size_t)grow * 128 + slot * 8;
      float4 a = *(const float4*)xp;
      float4 b = *(const float4*)(xp + 4);
      tmp[0] = f2bf(a.x); tmp[1] = f2bf(a.y); tmp[2] = f2bf(a.z); tmp[3] = f2bf(a.w);
      tmp[4] = f2bf(b.x); tmp[5] = f2bf(b.y); tmp[6] = f2bf(b.z); tmp[7] = f2bf(b.w);
    } else {
      *(uint4*)tmp = *(const uint4*)(ga.Xh + (size_t)grow * 128 + slot * 8);
    }
    *(uint4*)(&At[row * 128 + dsl * 8]) = *(const uint4*)tmp;
    *(uint4*)(&Bt[row * 128 + dsl * 8]) = *(const uint4*)(Wt + c * 8);
  }
  __syncthreads();

  int lane = threadIdx.x & 63, wv = threadIdx.x >> 6;
  int wm = wv >> 1, wn = wv & 1;
  int lr = lane & 15, lk = lane >> 4;
  f32x4 acc[4][4];
  #pragma unroll
  for (int mi = 0; mi < 4; ++mi)
    #pragma unroll
    for (int ni = 0; ni < 4; ++ni) acc[mi][ni] = (f32x4){0.f, 0.f, 0.f, 0.f};

  #pragma unroll
  for (int kk = 0; kk < 4; ++kk) {
    bf16x8 af[4], bfr[4];
    #pragma unroll
    for (int mi = 0; mi < 4; ++mi) {
      int row = wm * 64 + mi * 16 + lr;
      int slot = (kk * 4 + lk) ^ (row & 7);
      af[mi] = *(const bf16x8*)(&At[row * 128 + slot * 8]);
    }
    #pragma unroll
    for (int ni = 0; ni < 4; ++ni) {
      int row = wn * 64 + ni * 16 + lr;
      int slot = (kk * 4 + lk) ^ (row & 7);
      bfr[ni] = *(const bf16x8*)(&Bt[row * 128 + slot * 8]);
    }
    #pragma unroll
    for (int mi = 0; mi < 4; ++mi)
      #pragma unroll
      for (int ni = 0; ni < 4; ++ni)
        acc[mi][ni] = __builtin_amdgcn_mfma_f32_16x16x32_bf16(af[mi], bfr[ni], acc[mi][ni], 0, 0, 0);
  }

  const float* bias = which == 0 ? ga.b0 : which == 1 ? ga.b1 : which == 2 ? ga.b2 : ga.b3;
  float* outp = which == 0 ? ga.o0 : which == 1 ? ga.o1 : which == 2 ? ga.o2 : ga.o3;
  float bv[4];
  #pragma unroll
  for (int ni = 0; ni < 4; ++ni) bv[ni] = bias[wn * 64 + ni * 16 + lr];
  #pragma unroll
  for (int mi = 0; mi < 4; ++mi) {
    #pragma unroll
    for (int i = 0; i < 4; ++i) {
      int row = m0 + wm * 64 + mi * 16 + lk * 4 + i;
      if (row < ga.M) {
        #pragma unroll
        for (int ni = 0; ni < 4; ++ni) {
          int col = wn * 64 + ni * 16 + lr;
          outp[(size_t)row * 128 + col] = acc[mi][ni][i] + bv[ni];
        }
      }
    }
  }
}

// ---------------------------------------------------------------------------
// Per-dst-node fused attention: one wave per node, online softmax, e computed
// on the fly from register-resident We columns. CHALF lanes per head (C/2).
// ---------------------------------------------------------------------------
template<int CHALF, bool RELU, bool OUT_BF16>
__global__ __launch_bounds__(256) void edge_attn(
    const float* __restrict__ Q, const float* __restrict__ K,
    const float* __restrict__ V, const float* __restrict__ S,
    const float* __restrict__ We, const float* __restrict__ EA,
    const int2* __restrict__ eidx2, const int* __restrict__ rs,
    void* __restrict__ outv, float inv_sqrt_c) {
  int wv = threadIdx.x >> 6, lane = threadIdx.x & 63;
  int node = blockIdx.x * 4 + wv;
  if (node >= N_NODES) return;
  int c0 = lane * 2;  // this lane owns channels c0, c0+1

  float w0[16], w1[16];
  #pragma unroll
  for (int k = 0; k < 16; ++k) {
    float2 wp = *(const float2*)(We + k * 128 + c0);
    w0[k] = wp.x; w1[k] = wp.y;
  }
  float2 qv = *(const float2*)(Q + (size_t)node * 128 + c0);
  float qa = qv.x * inv_sqrt_c;
  float qb = qv.y * inv_sqrt_c;

  float m = -1e30f, den = 0.f, acc0 = 0.f, acc1 = 0.f;
  int i0 = rs[node], i1 = rs[node + 1];
  for (int i = i0; i < i1; ++i) {
    int2 es = eidx2[i];
    int e = es.x, s = es.y;
    const float4* ea4 = (const float4*)(EA + (size_t)e * 16);
    float4 r0 = ea4[0], r1 = ea4[1], r2 = ea4[2], r3 = ea4[3];
    float ea[16] = { r0.x, r0.y, r0.z, r0.w, r1.x, r1.y, r1.z, r1.w,
                     r2.x, r2.y, r2.z, r2.w, r3.x, r3.y, r3.z, r3.w };
    float2 kv = *(const float2*)(K + (size_t)s * 128 + c0);
    float2 vv = *(const float2*)(V + (size_t)s * 128 + c0);
    float e0 = 0.f, e1 = 0.f;
    #pragma unroll
    for (int j = 0; j < 16; ++j) { e0 += ea[j] * w0[j]; e1 += ea[j] * w1[j]; }
    float p = qa * (kv.x + e0) + qb * (kv.y + e1);
    #pragma unroll
    for (int off = 1; off < CHALF; off <<= 1) p += __shfl_xor(p, off, 64);
    float mn = fmaxf(m, p);
    float sc = __expf(m - mn);     // m=-1e30 initially -> 0
    float w  = __expf(p - mn);
    den  = den * sc + w;
    acc0 = acc0 * sc + w * (vv.x + e0);
    acc1 = acc1 * sc + w * (vv.y + e1);
    m = mn;
  }
  float inv = 1.f / (den + 1e-16f);   // deg==0: acc=0 -> agg=0
  float2 sk = *(const float2*)(S + (size_t)node * 128 + c0);
  float o0 = acc0 * inv + sk.x;
  float o1 = acc1 * inv + sk.y;
  if (RELU) { o0 = fmaxf(o0, 0.f); o1 = fmaxf(o1, 0.f); }
  if (OUT_BF16) {
    unsigned int op = ((unsigned int)f2bf(o1) << 16) | (unsigned int)f2bf(o0);
    *(unsigned int*)((unsigned short*)outv + (size_t)node * 128 + c0) = op;
  } else {
    *(float2*)((float*)outv + (size_t)node * 128 + c0) = make_float2(o0, o1);
  }
}

// ---------------------------------------------------------------------------
extern "C" void kernel_launch(void* const* d_in, const int* in_sizes, int n_in,
                              void* d_out, int out_size, void* d_ws, size_t ws_size,
                              hipStream_t stream) {
  const float* x   = (const float*)d_in[0];
  const int*   ei  = (const int*)d_in[1];
  const float* ea  = (const float*)d_in[2];
  const float* Wq0 = (const float*)d_in[3];
  const float* bq0 = (const float*)d_in[4];
  const float* Wk0 = (const float*)d_in[5];
  const float* bk0 = (const float*)d_in[6];
  const float* Wv0 = (const float*)d_in[7];
  const float* bv0 = (const float*)d_in[8];
  const float* We0 = (const float*)d_in[9];
  const float* Ws0 = (const float*)d_in[10];
  const float* bs0 = (const float*)d_in[11];
  const float* Wq1 = (const float*)d_in[12];
  const float* bq1 = (const float*)d_in[13];
  const float* Wk1 = (const float*)d_in[14];
  const float* bk1 = (const float*)d_in[15];
  const float* Wv1 = (const float*)d_in[16];
  const float* bv1 = (const float*)d_in[17];
  const float* We1 = (const float*)d_in[18];
  const float* Ws1 = (const float*)d_in[19];
  const float* bs1 = (const float*)d_in[20];

  char* ws = (char*)d_ws;
  size_t off = 0;
  auto alloc = [&](size_t bytes) -> void* {
    void* p = ws + off;
    off = (off + bytes + 255) & ~(size_t)255;
    return p;
  };
  unsigned short* WT = (unsigned short*)alloc(8 * 16384 * 2);            // 256 KB bf16
  float* q    = (float*)alloc((size_t)N_NODES * 128 * 4);                // 25.6 MB
  float* k    = (float*)alloc((size_t)N_NODES * 128 * 4);
  float* v    = (float*)alloc((size_t)N_NODES * 128 * 4);
  float* s    = (float*)alloc((size_t)N_NODES * 128 * 4);
  unsigned short* h = (unsigned short*)alloc((size_t)N_NODES * 128 * 2); // 12.8 MB bf16
  int* cnt    = (int*)alloc(N_NODES * 4);
  int* rs     = (int*)alloc((N_NODES + 1) * 4);
  int* cursor = (int*)alloc(N_NODES * 4);
  int2* eidx2 = (int2*)alloc((size_t)N_EDGES * 8);                       // 6.4 MB

  const int* srcp = ei;
  const int* dstp = ei + N_EDGES;

  // one-time-per-launch prep
  Ptr8 p8 = {{Wq0, Wk0, Wv0, Ws0, Wq1, Wk1, Wv1, Ws1}};
  transpose_w<<<8, 256, 0, stream>>>(p8, WT);
  zero_kernel<<<196, 256, 0, stream>>>(cnt, cursor);
  hist_kernel<<<3125, 256, 0, stream>>>(dstp, cnt);
  scan_kernel<<<1, 1024, 0, stream>>>(cnt, rs);
  scatter_kernel<<<3125, 256, 0, stream>>>(srcp, dstp, rs, cursor, eidx2);

  // layer 0: q/k/v/s = x @ {Wq0,Wk0,Wv0,Ws0} + b
  GemmArgs ga0 = { x, nullptr, WT, bq0, bk0, bv0, bs0, q, k, v, s, N_NODES };
  node_gemm<true><<<dim3(391, 4), 256, 0, stream>>>(ga0);
  edge_attn<8, true, true><<<12500, 256, 0, stream>>>(q, k, v, s, We0, ea, eidx2, rs,
                                                      h, 0.25f);

  // layer 1: q/k/v/s = h @ {Wq1,Wk1,Wv1,Ws1} + b
  GemmArgs ga1 = { nullptr, h, WT + 4 * 16384, bq1, bk1, bv1, bs1, q, k, v, s, N_NODES };
  node_gemm<false><<<dim3(391, 4), 256, 0, stream>>>(ga1);
  edge_attn<64, false, false><<<12500, 256, 0, stream>>>(q, k, v, s, We1, ea, eidx2, rs,
                                                         d_out, 0.08838834764831845f);
}

// Round 3
// 792.059 us; speedup vs baseline: 1.0856x; 1.0856x over previous
//
#include <hip/hip_runtime.h>
#include <stdint.h>

#define N_NODES 50000
#define N_EDGES 800000

typedef __bf16 bf16x8 __attribute__((ext_vector_type(8)));
typedef float f32x4 __attribute__((ext_vector_type(4)));

__device__ __forceinline__ unsigned short f2bf(float f) {
  union { float f; unsigned int i; } x; x.f = f;
  unsigned int i = x.i;
  unsigned int r = (i + 0x7fffu + ((i >> 16) & 1u)) >> 16;  // round-nearest-even
  return (unsigned short)r;
}
__device__ __forceinline__ float bfl(unsigned int p) {           // low bf16 -> f32
  union { unsigned int i; float f; } x; x.i = p << 16; return x.f;
}
__device__ __forceinline__ float bfh(unsigned int p) {           // high bf16 -> f32
  union { unsigned int i; float f; } x; x.i = p & 0xffff0000u; return x.f;
}

// ---------------------------------------------------------------------------
// Weight transpose+convert: W f32 [k=128][n=128] -> Wt bf16 [n][k].
// 8 matrices packed at Wt + mat*16384.
// ---------------------------------------------------------------------------
struct Ptr8 { const float* p[8]; };

__global__ __launch_bounds__(256) void transpose_w(Ptr8 ws, unsigned short* wt) {
  int mat = blockIdx.x;
  const float* W = ws.p[mat];
  unsigned short* out = wt + mat * 16384;
  for (int it = 0; it < 64; ++it) {
    int idx = it * 256 + threadIdx.x;
    int n = idx >> 7, k = idx & 127;
    out[n * 128 + k] = f2bf(W[k * 128 + n]);
  }
}

// ---------------------------------------------------------------------------
// CSR build
// ---------------------------------------------------------------------------
__global__ void zero_kernel(int* cnt, int* cursor) {
  int i = blockIdx.x * blockDim.x + threadIdx.x;
  if (i < N_NODES) { cnt[i] = 0; cursor[i] = 0; }
}

__global__ void hist_kernel(const int* __restrict__ dst, int* __restrict__ cnt) {
  int e = blockIdx.x * blockDim.x + threadIdx.x;
  if (e < N_EDGES) atomicAdd(&cnt[dst[e]], 1);
}

__global__ __launch_bounds__(1024) void scan_kernel(const int* __restrict__ cnt, int* __restrict__ rs) {
  const int n = N_NODES, per = 49;  // ceil(50000/1024)
  int t = threadIdx.x;
  int lo = t * per; int hi = lo + per;
  if (lo > n) lo = n;
  if (hi > n) hi = n;
  int s = 0;
  for (int i = lo; i < hi; ++i) s += cnt[i];
  int lane = t & 63, wv = t >> 6;
  int v = s;
  #pragma unroll
  for (int off = 1; off < 64; off <<= 1) {
    int u = __shfl_up(v, off, 64);
    if (lane >= off) v += u;
  }
  __shared__ int wsum[16], woff[16];
  if (lane == 63) wsum[wv] = v;
  __syncthreads();
  if (t == 0) { int a = 0; for (int w = 0; w < 16; ++w) { woff[w] = a; a += wsum[w]; } }
  __syncthreads();
  int run = woff[wv] + (v - s);
  if (t == 0) rs[0] = 0;
  for (int i = lo; i < hi; ++i) { run += cnt[i]; rs[i + 1] = run; }
}

__global__ void scatter_kernel(const int* __restrict__ src, const int* __restrict__ dst,
                               const int* __restrict__ rs, int* __restrict__ cursor,
                               int2* __restrict__ eidx2) {
  int e = blockIdx.x * blockDim.x + threadIdx.x;
  if (e < N_EDGES) {
    int d = dst[e];
    int pos = atomicAdd(&cursor[d], 1);
    eidx2[rs[d] + pos] = make_int2(e, src[e]);
  }
}

// ---------------------------------------------------------------------------
// Node GEMM: out = X @ W + b -> bf16. X f32 (layer 0) or bf16 (layer 1).
// W pre-transposed bf16 [n][k]; 4 weight mats via blockIdx.y.
// 128x128 tile, 4 waves 2x2, XOR-swizzled LDS.
// ---------------------------------------------------------------------------
struct GemmArgs {
  const float* Xf;
  const unsigned short* Xh;
  const unsigned short* Wt;
  const float* b0; const float* b1; const float* b2; const float* b3;
  unsigned short* o0; unsigned short* o1; unsigned short* o2; unsigned short* o3;
  int M;
};

template<bool XF32>
__global__ __launch_bounds__(256) void node_gemm(GemmArgs ga) {
  __shared__ alignas(16) unsigned short At[128 * 128];
  __shared__ alignas(16) unsigned short Bt[128 * 128];
  int which = blockIdx.y;
  const unsigned short* Wt = ga.Wt + which * 16384;
  int m0 = blockIdx.x * 128;

  #pragma unroll
  for (int it = 0; it < 8; ++it) {
    int c = it * 256 + threadIdx.x;        // chunk id, 0..2047
    int row = c >> 4, slot = c & 15;
    int dsl = slot ^ (row & 7);
    int grow = m0 + row; if (grow >= ga.M) grow = ga.M - 1;
    alignas(16) unsigned short tmp[8];
    if (XF32) {
      const float* xp = ga.Xf + (size_t)grow * 128 + slot * 8;
      float4 a = *(const float4*)xp;
      float4 b = *(const float4*)(xp + 4);
      tmp[0] = f2bf(a.x); tmp[1] = f2bf(a.y); tmp[2] = f2bf(a.z); tmp[3] = f2bf(a.w);
      tmp[4] = f2bf(b.x); tmp[5] = f2bf(b.y); tmp[6] = f2bf(b.z); tmp[7] = f2bf(b.w);
    } else {
      *(uint4*)tmp = *(const uint4*)(ga.Xh + (size_t)grow * 128 + slot * 8);
    }
    *(uint4*)(&At[row * 128 + dsl * 8]) = *(const uint4*)tmp;
    *(uint4*)(&Bt[row * 128 + dsl * 8]) = *(const uint4*)(Wt + c * 8);
  }
  __syncthreads();

  int lane = threadIdx.x & 63, wv = threadIdx.x >> 6;
  int wm = wv >> 1, wn = wv & 1;
  int lr = lane & 15, lk = lane >> 4;
  f32x4 acc[4][4];
  #pragma unroll
  for (int mi = 0; mi < 4; ++mi)
    #pragma unroll
    for (int ni = 0; ni < 4; ++ni) acc[mi][ni] = (f32x4){0.f, 0.f, 0.f, 0.f};

  #pragma unroll
  for (int kk = 0; kk < 4; ++kk) {
    bf16x8 af[4], bfr[4];
    #pragma unroll
    for (int mi = 0; mi < 4; ++mi) {
      int row = wm * 64 + mi * 16 + lr;
      int slot = (kk * 4 + lk) ^ (row & 7);
      af[mi] = *(const bf16x8*)(&At[row * 128 + slot * 8]);
    }
    #pragma unroll
    for (int ni = 0; ni < 4; ++ni) {
      int row = wn * 64 + ni * 16 + lr;
      int slot = (kk * 4 + lk) ^ (row & 7);
      bfr[ni] = *(const bf16x8*)(&Bt[row * 128 + slot * 8]);
    }
    #pragma unroll
    for (int mi = 0; mi < 4; ++mi)
      #pragma unroll
      for (int ni = 0; ni < 4; ++ni)
        acc[mi][ni] = __builtin_amdgcn_mfma_f32_16x16x32_bf16(af[mi], bfr[ni], acc[mi][ni], 0, 0, 0);
  }

  const float* bias = which == 0 ? ga.b0 : which == 1 ? ga.b1 : which == 2 ? ga.b2 : ga.b3;
  unsigned short* outp = which == 0 ? ga.o0 : which == 1 ? ga.o1 : which == 2 ? ga.o2 : ga.o3;
  float bv[4];
  #pragma unroll
  for (int ni = 0; ni < 4; ++ni) bv[ni] = bias[wn * 64 + ni * 16 + lr];
  #pragma unroll
  for (int mi = 0; mi < 4; ++mi) {
    #pragma unroll
    for (int i = 0; i < 4; ++i) {
      int row = m0 + wm * 64 + mi * 16 + lk * 4 + i;
      if (row < ga.M) {
        #pragma unroll
        for (int ni = 0; ni < 4; ++ni) {
          int col = wn * 64 + ni * 16 + lr;
          outp[(size_t)row * 128 + col] = f2bf(acc[mi][ni][i] + bv[ni]);
        }
      }
    }
  }
}

// ---------------------------------------------------------------------------
// Per-dst-node fused attention, bf16 q/k/v/s, pair-wise online softmax with
// 1-pair-ahead prefetch (4 edges in flight per wave).
// ---------------------------------------------------------------------------
struct EdgeLd {
  float ea[16];          // edge_attr row (broadcast)
  unsigned int kp, vp;   // packed 2x bf16 for this lane's channels
};

__device__ __forceinline__ void edge_issue(int ja, const float* __restrict__ EA,
                                           const unsigned short* __restrict__ K,
                                           const unsigned short* __restrict__ V,
                                           const int2* __restrict__ eidx2,
                                           int c0, EdgeLd& L) {
  int2 es = eidx2[ja];
  const float4* p = (const float4*)(EA + (size_t)es.x * 16);
  *(float4*)(&L.ea[0])  = p[0];
  *(float4*)(&L.ea[4])  = p[1];
  *(float4*)(&L.ea[8])  = p[2];
  *(float4*)(&L.ea[12]) = p[3];
  L.kp = *(const unsigned int*)(K + (size_t)es.y * 128 + c0);
  L.vp = *(const unsigned int*)(V + (size_t)es.y * 128 + c0);
}

template<int CHALF, bool RELU, bool OUT_BF16>
__global__ __launch_bounds__(256) void edge_attn(
    const unsigned short* __restrict__ Q, const unsigned short* __restrict__ K,
    const unsigned short* __restrict__ V, const unsigned short* __restrict__ S,
    const float* __restrict__ We, const float* __restrict__ EA,
    const int2* __restrict__ eidx2, const int* __restrict__ rs,
    void* __restrict__ outv, float inv_sqrt_c) {
  int wv = threadIdx.x >> 6, lane = threadIdx.x & 63;
  int node = blockIdx.x * 4 + wv;
  if (node >= N_NODES) return;
  int c0 = lane * 2;

  float w0[16], w1[16];
  #pragma unroll
  for (int k = 0; k < 16; ++k) {
    float2 wp = *(const float2*)(We + k * 128 + c0);
    w0[k] = wp.x; w1[k] = wp.y;
  }
  unsigned int qp = *(const unsigned int*)(Q + (size_t)node * 128 + c0);
  float qa = bfl(qp) * inv_sqrt_c;
  float qb = bfh(qp) * inv_sqrt_c;

  float m = -1e30f, den = 0.f, acc0 = 0.f, acc1 = 0.f;
  int i0 = rs[node], i1 = rs[node + 1];
  int P = (i1 - i0 + 1) >> 1;   // number of pairs (odd tail folded in)

  EdgeLd A0, B0, A1, B1;

  auto compute = [&](int g, const EdgeLd& LA, const EdgeLd& LB) {
    float eA0 = 0.f, eA1 = 0.f, eB0 = 0.f, eB1 = 0.f;
    #pragma unroll
    for (int j = 0; j < 16; ++j) {
      eA0 += LA.ea[j] * w0[j]; eA1 += LA.ea[j] * w1[j];
      eB0 += LB.ea[j] * w0[j]; eB1 += LB.ea[j] * w1[j];
    }
    float kAx = bfl(LA.kp), kAy = bfh(LA.kp);
    float kBx = bfl(LB.kp), kBy = bfh(LB.kp);
    float vAx = bfl(LA.vp), vAy = bfh(LA.vp);
    float vBx = bfl(LB.vp), vBy = bfh(LB.vp);
    float pA = qa * (kAx + eA0) + qb * (kAy + eA1);
    float pB = qa * (kBx + eB0) + qb * (kBy + eB1);
    #pragma unroll
    for (int off = 1; off < CHALF; off <<= 1) {
      pA += __shfl_xor(pA, off, 64);
      pB += __shfl_xor(pB, off, 64);
    }
    if (g + 1 >= i1) pB = -1e30f;            // folded odd tail contributes 0
    float mn = fmaxf(m, fmaxf(pA, pB));
    float sc = __expf(m - mn);
    float wA = __expf(pA - mn);
    float wB = __expf(pB - mn);
    den  = den * sc + wA + wB;
    acc0 = acc0 * sc + wA * (vAx + eA0) + wB * (vBx + eB0);
    acc1 = acc1 * sc + wA * (vAy + eA1) + wB * (vBy + eB1);
    m = mn;
  };
  auto loadp = [&](int p, EdgeLd& LA, EdgeLd& LB) {
    int ja = i0 + 2 * p;
    int jb = ja + 1 < i1 ? ja + 1 : i1 - 1;  // clamped (value masked later)
    edge_issue(ja, EA, K, V, eidx2, c0, LA);
    edge_issue(jb, EA, K, V, eidx2, c0, LB);
  };

  if (P > 0) {
    loadp(0, A0, B0);
    for (int p = 0; p < P; p += 2) {
      if (p + 1 < P) loadp(p + 1, A1, B1);   // prefetch next pair
      compute(i0 + 2 * p, A0, B0);
      if (p + 2 < P) loadp(p + 2, A0, B0);   // prefetch pair after
      if (p + 1 < P) compute(i0 + 2 * (p + 1), A1, B1);
    }
  }

  float inv = 1.f / (den + 1e-16f);
  unsigned int sp = *(const unsigned int*)(S + (size_t)node * 128 + c0);
  float o0 = acc0 * inv + bfl(sp);
  float o1 = acc1 * inv + bfh(sp);
  if (RELU) { o0 = fmaxf(o0, 0.f); o1 = fmaxf(o1, 0.f); }
  if (OUT_BF16) {
    unsigned int op = ((unsigned int)f2bf(o1) << 16) | (unsigned int)f2bf(o0);
    *(unsigned int*)((unsigned short*)outv + (size_t)node * 128 + c0) = op;
  } else {
    *(float2*)((float*)outv + (size_t)node * 128 + c0) = make_float2(o0, o1);
  }
}

// ---------------------------------------------------------------------------
extern "C" void kernel_launch(void* const* d_in, const int* in_sizes, int n_in,
                              void* d_out, int out_size, void* d_ws, size_t ws_size,
                              hipStream_t stream) {
  const float* x   = (const float*)d_in[0];
  const int*   ei  = (const int*)d_in[1];
  const float* ea  = (const float*)d_in[2];
  const float* Wq0 = (const float*)d_in[3];
  const float* bq0 = (const float*)d_in[4];
  const float* Wk0 = (const float*)d_in[5];
  const float* bk0 = (const float*)d_in[6];
  const float* Wv0 = (const float*)d_in[7];
  const float* bv0 = (const float*)d_in[8];
  const float* We0 = (const float*)d_in[9];
  const float* Ws0 = (const float*)d_in[10];
  const float* bs0 = (const float*)d_in[11];
  const float* Wq1 = (const float*)d_in[12];
  const float* bq1 = (const float*)d_in[13];
  const float* Wk1 = (const float*)d_in[14];
  const float* bk1 = (const float*)d_in[15];
  const float* Wv1 = (const float*)d_in[16];
  const float* bv1 = (const float*)d_in[17];
  const float* We1 = (const float*)d_in[18];
  const float* Ws1 = (const float*)d_in[19];
  const float* bs1 = (const float*)d_in[20];

  char* ws = (char*)d_ws;
  size_t off = 0;
  auto alloc = [&](size_t bytes) -> void* {
    void* p = ws + off;
    off = (off + bytes + 255) & ~(size_t)255;
    return p;
  };
  unsigned short* WT = (unsigned short*)alloc(8 * 16384 * 2);              // 256 KB bf16
  unsigned short* q  = (unsigned short*)alloc((size_t)N_NODES * 128 * 2);  // 12.8 MB each
  unsigned short* k  = (unsigned short*)alloc((size_t)N_NODES * 128 * 2);
  unsigned short* v  = (unsigned short*)alloc((size_t)N_NODES * 128 * 2);
  unsigned short* s  = (unsigned short*)alloc((size_t)N_NODES * 128 * 2);
  unsigned short* h  = (unsigned short*)alloc((size_t)N_NODES * 128 * 2);
  int* cnt    = (int*)alloc(N_NODES * 4);
  int* rs     = (int*)alloc((N_NODES + 1) * 4);
  int* cursor = (int*)alloc(N_NODES * 4);
  int2* eidx2 = (int2*)alloc((size_t)N_EDGES * 8);                         // 6.4 MB

  const int* srcp = ei;
  const int* dstp = ei + N_EDGES;

  Ptr8 p8 = {{Wq0, Wk0, Wv0, Ws0, Wq1, Wk1, Wv1, Ws1}};
  transpose_w<<<8, 256, 0, stream>>>(p8, WT);
  zero_kernel<<<196, 256, 0, stream>>>(cnt, cursor);
  hist_kernel<<<3125, 256, 0, stream>>>(dstp, cnt);
  scan_kernel<<<1, 1024, 0, stream>>>(cnt, rs);
  scatter_kernel<<<3125, 256, 0, stream>>>(srcp, dstp, rs, cursor, eidx2);

  // layer 0
  GemmArgs ga0 = { x, nullptr, WT, bq0, bk0, bv0, bs0, q, k, v, s, N_NODES };
  node_gemm<true><<<dim3(391, 4), 256, 0, stream>>>(ga0);
  edge_attn<8, true, true><<<12500, 256, 0, stream>>>(q, k, v, s, We0, ea, eidx2, rs,
                                                      h, 0.25f);

  // layer 1
  GemmArgs ga1 = { nullptr, h, WT + 4 * 16384, bq1, bk1, bv1, bs1, q, k, v, s, N_NODES };
  node_gemm<false><<<dim3(391, 4), 256, 0, stream>>>(ga1);
  edge_attn<64, false, false><<<12500, 256, 0, stream>>>(q, k, v, s, We1, ea, eidx2, rs,
                                                         d_out, 0.08838834764831845f);
}

// Round 5
// 672.811 us; speedup vs baseline: 1.2780x; 1.1772x over previous
//
#include <hip/hip_runtime.h>
#include <stdint.h>

#define N_NODES 50000
#define N_EDGES 800000

typedef __bf16 bf16x8 __attribute__((ext_vector_type(8)));
typedef float f32x4 __attribute__((ext_vector_type(4)));

__device__ __forceinline__ unsigned short f2bf(float f) {
  union { float f; unsigned int i; } x; x.f = f;
  unsigned int i = x.i;
  unsigned int r = (i + 0x7fffu + ((i >> 16) & 1u)) >> 16;  // round-nearest-even
  return (unsigned short)r;
}
__device__ __forceinline__ float bfl(unsigned int p) {
  union { unsigned int i; float f; } x; x.i = p << 16; return x.f;
}
__device__ __forceinline__ float bfh(unsigned int p) {
  union { unsigned int i; float f; } x; x.i = p & 0xffff0000u; return x.f;
}

// ---------------------------------------------------------------------------
// Weight transpose+convert: W f32 [k=128][n=128] -> Wt bf16 [n][k].
// ---------------------------------------------------------------------------
struct Ptr8 { const float* p[8]; };

__global__ __launch_bounds__(256) void transpose_w(Ptr8 ws, unsigned short* wt) {
  int mat = blockIdx.x;
  const float* W = ws.p[mat];
  unsigned short* out = wt + mat * 16384;
  for (int it = 0; it < 64; ++it) {
    int idx = it * 256 + threadIdx.x;
    int n = idx >> 7, k = idx & 127;
    out[n * 128 + k] = f2bf(W[k * 128 + n]);
  }
}

// ---------------------------------------------------------------------------
// CSR build
// ---------------------------------------------------------------------------
__global__ void zero_kernel(int* cnt, int* cursor, int* pad) {
  int i = blockIdx.x * blockDim.x + threadIdx.x;
  if (i < N_NODES) { cnt[i] = 0; cursor[i] = 0; }
  if (i < 16) pad[i] = 0;   // zero 8 int2 pad entries after eidx2
}

__global__ void hist_kernel(const int* __restrict__ dst, int* __restrict__ cnt) {
  int e = blockIdx.x * blockDim.x + threadIdx.x;
  if (e < N_EDGES) atomicAdd(&cnt[dst[e]], 1);
}

__global__ __launch_bounds__(1024) void scan_kernel(const int* __restrict__ cnt, int* __restrict__ rs) {
  const int n = N_NODES, per = 49;
  int t = threadIdx.x;
  int lo = t * per; int hi = lo + per;
  if (lo > n) lo = n;
  if (hi > n) hi = n;
  int s = 0;
  for (int i = lo; i < hi; ++i) s += cnt[i];
  int lane = t & 63, wv = t >> 6;
  int v = s;
  #pragma unroll
  for (int off = 1; off < 64; off <<= 1) {
    int u = __shfl_up(v, off, 64);
    if (lane >= off) v += u;
  }
  __shared__ int wsum[16], woff[16];
  if (lane == 63) wsum[wv] = v;
  __syncthreads();
  if (t == 0) { int a = 0; for (int w = 0; w < 16; ++w) { woff[w] = a; a += wsum[w]; } }
  __syncthreads();
  int run = woff[wv] + (v - s);
  if (t == 0) rs[0] = 0;
  for (int i = lo; i < hi; ++i) { run += cnt[i]; rs[i + 1] = run; }
}

__global__ void scatter_kernel(const int* __restrict__ src, const int* __restrict__ dst,
                               const int* __restrict__ rs, int* __restrict__ cursor,
                               int2* __restrict__ eidx2) {
  int e = blockIdx.x * blockDim.x + threadIdx.x;
  if (e < N_EDGES) {
    int d = dst[e];
    int pos = rs[d] + atomicAdd(&cursor[d], 1);
    eidx2[pos] = make_int2(src[e], e);   // {src node, edge id}
  }
}

// ---------------------------------------------------------------------------
// Node GEMM: {q,k,v,s} = X @ W + b -> bf16. k,v interleaved into KV buffer:
// ushort idx = node*256 + (col>>1)*4 + (isV?2:0) + (col&1)   (uint2 per lane)
// ---------------------------------------------------------------------------
struct GemmArgs {
  const float* Xf;
  const unsigned short* Xh;
  const unsigned short* Wt;
  const float* b0; const float* b1; const float* b2; const float* b3;
  unsigned short* qb;
  unsigned short* kvb;
  unsigned short* sb;
  int M;
};

template<bool XF32>
__global__ __launch_bounds__(256) void node_gemm(GemmArgs ga) {
  __shared__ alignas(16) unsigned short At[128 * 128];
  __shared__ alignas(16) unsigned short Bt[128 * 128];
  int which = blockIdx.y;
  const unsigned short* Wt = ga.Wt + which * 16384;
  int m0 = blockIdx.x * 128;

  #pragma unroll
  for (int it = 0; it < 8; ++it) {
    int c = it * 256 + threadIdx.x;
    int row = c >> 4, slot = c & 15;
    int dsl = slot ^ (row & 7);
    int grow = m0 + row; if (grow >= ga.M) grow = ga.M - 1;
    alignas(16) unsigned short tmp[8];
    if (XF32) {
      const float* xp = ga.Xf + (size_t)grow * 128 + slot * 8;
      float4 a = *(const float4*)xp;
      float4 b = *(const float4*)(xp + 4);
      tmp[0] = f2bf(a.x); tmp[1] = f2bf(a.y); tmp[2] = f2bf(a.z); tmp[3] = f2bf(a.w);
      tmp[4] = f2bf(b.x); tmp[5] = f2bf(b.y); tmp[6] = f2bf(b.z); tmp[7] = f2bf(b.w);
    } else {
      *(uint4*)tmp = *(const uint4*)(ga.Xh + (size_t)grow * 128 + slot * 8);
    }
    *(uint4*)(&At[row * 128 + dsl * 8]) = *(const uint4*)tmp;
    *(uint4*)(&Bt[row * 128 + dsl * 8]) = *(const uint4*)(Wt + c * 8);
  }
  __syncthreads();

  int lane = threadIdx.x & 63, wv = threadIdx.x >> 6;
  int wm = wv >> 1, wn = wv & 1;
  int lr = lane & 15, lk = lane >> 4;
  f32x4 acc[4][4];
  #pragma unroll
  for (int mi = 0; mi < 4; ++mi)
    #pragma unroll
    for (int ni = 0; ni < 4; ++ni) acc[mi][ni] = (f32x4){0.f, 0.f, 0.f, 0.f};

  #pragma unroll
  for (int kk = 0; kk < 4; ++kk) {
    bf16x8 af[4], bfr[4];
    #pragma unroll
    for (int mi = 0; mi < 4; ++mi) {
      int row = wm * 64 + mi * 16 + lr;
      int slot = (kk * 4 + lk) ^ (row & 7);
      af[mi] = *(const bf16x8*)(&At[row * 128 + slot * 8]);
    }
    #pragma unroll
    for (int ni = 0; ni < 4; ++ni) {
      int row = wn * 64 + ni * 16 + lr;
      int slot = (kk * 4 + lk) ^ (row & 7);
      bfr[ni] = *(const bf16x8*)(&Bt[row * 128 + slot * 8]);
    }
    #pragma unroll
    for (int mi = 0; mi < 4; ++mi)
      #pragma unroll
      for (int ni = 0; ni < 4; ++ni)
        acc[mi][ni] = __builtin_amdgcn_mfma_f32_16x16x32_bf16(af[mi], bfr[ni], acc[mi][ni], 0, 0, 0);
  }

  const float* bias = which == 0 ? ga.b0 : which == 1 ? ga.b1 : which == 2 ? ga.b2 : ga.b3;
  float bv[4];
  #pragma unroll
  for (int ni = 0; ni < 4; ++ni) bv[ni] = bias[wn * 64 + ni * 16 + lr];
  #pragma unroll
  for (int mi = 0; mi < 4; ++mi) {
    #pragma unroll
    for (int i = 0; i < 4; ++i) {
      int row = m0 + wm * 64 + mi * 16 + lk * 4 + i;
      if (row < ga.M) {
        #pragma unroll
        for (int ni = 0; ni < 4; ++ni) {
          int col = wn * 64 + ni * 16 + lr;
          unsigned short val = f2bf(acc[mi][ni][i] + bv[ni]);
          if (which == 0)      ga.qb[(size_t)row * 128 + col] = val;
          else if (which == 3) ga.sb[(size_t)row * 128 + col] = val;
          else {
            size_t base = (size_t)row * 256 + (size_t)(col >> 1) * 4 + (col & 1);
            ga.kvb[base + (which == 2 ? 2 : 0)] = val;
          }
        }
      }
    }
  }
}

// ---------------------------------------------------------------------------
// Per-dst-node fused attention v3: edge-MLP algebraically factored out.
//   alpha_e = q.k/sqrtC + (q@We_h).ea_e/sqrtC   (qWe precomputed per node)
//   out     = (sum w.v + (sum w.ea)@We) / den + skip
// No max subtraction (alphas O(1)) -> no serial chain. 8-edge chunks,
// 3-stage pipeline, static double buffers. j-ownership: lane owns
// jbase = 8*b0+4*b1+2*b2 (bits of lane), 2 j's per lane per 8-lane group.
// ---------------------------------------------------------------------------
template<int CHALF, bool RELU, bool OUT_BF16>
__global__ __launch_bounds__(256) void edge_attn(
    const unsigned short* __restrict__ Q, const uint2* __restrict__ KV,
    const unsigned short* __restrict__ S, const float* __restrict__ We,
    const float* __restrict__ EA, const int2* __restrict__ eidx2,
    const int* __restrict__ rs, void* __restrict__ outv, float inv_sqrt_c) {
  int wv = threadIdx.x >> 6, lane = threadIdx.x & 63;
  int node = blockIdx.x * 4 + wv;
  if (node >= N_NODES) return;
  int c0 = lane * 2;
  int jbase = (lane & 1) * 8 + ((lane >> 1) & 1) * 4 + ((lane >> 2) & 1) * 2;

  unsigned int qp = *(const unsigned int*)(Q + (size_t)node * 128 + c0);
  float qa = bfl(qp) * inv_sqrt_c;
  float qb = bfh(qp) * inv_sqrt_c;

  // ---- qWe[j] = sum_c q[c]*We[j][c] over this 8-lane group's channels ----
  float part[16];
  #pragma unroll
  for (int j = 0; j < 16; ++j) {
    float2 wp = *(const float2*)(We + j * 128 + c0);
    part[j] = qa * wp.x + qb * wp.y;
  }
  {  // reduce-scatter over lanes bits 0..2: 16 -> 8 -> 4 -> 2 values
    bool hi = lane & 1;
    #pragma unroll
    for (int j = 0; j < 8; ++j) {
      float kept = hi ? part[j + 8] : part[j];
      float sent = hi ? part[j] : part[j + 8];
      part[j] = kept + __shfl_xor(sent, 1, 64);
    }
    hi = lane & 2;
    #pragma unroll
    for (int j = 0; j < 4; ++j) {
      float kept = hi ? part[j + 4] : part[j];
      float sent = hi ? part[j] : part[j + 4];
      part[j] = kept + __shfl_xor(sent, 2, 64);
    }
    hi = lane & 4;
    #pragma unroll
    for (int j = 0; j < 2; ++j) {
      float kept = hi ? part[j + 2] : part[j];
      float sent = hi ? part[j] : part[j + 2];
      part[j] = kept + __shfl_xor(sent, 4, 64);
    }
  }
  if (CHALF == 64) {  // finish sum over remaining lane bits; replicas x8
    #pragma unroll
    for (int s = 8; s <= 32; s <<= 1) {
      part[0] += __shfl_xor(part[0], s, 64);
      part[1] += __shfl_xor(part[1], s, 64);
    }
  }
  // layer1: j-partials replicated 8x in the 64-lane alpha reduce -> scale 1/8
  float qw0 = part[0] * (CHALF == 64 ? 0.125f : 1.0f);
  float qw1 = part[1] * (CHALF == 64 ? 0.125f : 1.0f);

  int i0 = rs[node], i1 = rs[node + 1];
  int deg = i1 - i0;
  float den = 0.f, a0 = 0.f, a1 = 0.f, wea0 = 0.f, wea1 = 0.f;

  struct Buf { uint2 kv[8]; float ea0[8]; float ea1[8]; };
  Buf bA, bB;
  int2 ceA, ceB;

  auto load_ce = [&](int c) -> int2 {
    return eidx2[i0 + c * 8 + (lane & 7)];
  };
  auto gather = [&](Buf& b, const int2& ce) {
    #pragma unroll
    for (int j = 0; j < 8; ++j) {
      int sv = __shfl(ce.x, j, 64);
      int ei = __shfl(ce.y, j, 64);
      b.kv[j] = KV[(size_t)sv * 64 + lane];
      float2 ep = *(const float2*)(EA + (size_t)ei * 16 + jbase);
      b.ea0[j] = ep.x; b.ea1[j] = ep.y;
    }
  };
  auto compute = [&](const Buf& b, int c) {
    #pragma unroll
    for (int j = 0; j < 8; ++j) {
      int g = i0 + c * 8 + j;
      uint2 kv = b.kv[j];
      float p = qa * bfl(kv.x) + qb * bfh(kv.x) + qw0 * b.ea0[j] + qw1 * b.ea1[j];
      #pragma unroll
      for (int off = 1; off < CHALF; off <<= 1) p += __shfl_xor(p, off, 64);
      float w = (g < i1) ? __expf(p) : 0.f;
      den  += w;
      a0   += w * bfl(kv.y);
      a1   += w * bfh(kv.y);
      wea0 += w * b.ea0[j];
      wea1 += w * b.ea1[j];
    }
  };

  int nch = (deg + 7) >> 3;
  if (nch > 0) {
    ceA = load_ce(0);
    if (nch > 1) ceB = load_ce(1);
    gather(bA, ceA);
    int c = 0;
    while (true) {
      if (c + 1 < nch) gather(bB, ceB);
      if (c + 2 < nch) ceA = load_ce(c + 2);
      compute(bA, c);
      ++c; if (c >= nch) break;
      if (c + 1 < nch) gather(bA, ceA);
      if (c + 2 < nch) ceB = load_ce(c + 2);
      compute(bB, c);
      ++c; if (c >= nch) break;
    }
  }

  // ---- epilogue: (a + wea@We)/den + skip ----
  float inv = 1.f / (den + 1e-16f);
  float eadd0 = 0.f, eadd1 = 0.f;
  #pragma unroll
  for (int j = 0; j < 16; ++j) {
    int owner = ((j >> 3) & 1) | (((j >> 2) & 1) << 1) | (((j >> 1) & 1) << 2);
    int srcl = (lane & 56) | owner;
    float val = __shfl((j & 1) ? wea1 : wea0, srcl, 64);
    float2 wp = *(const float2*)(We + j * 128 + c0);
    eadd0 += val * wp.x;
    eadd1 += val * wp.y;
  }
  unsigned int sp = *(const unsigned int*)(S + (size_t)node * 128 + c0);
  float o0 = (a0 + eadd0) * inv + bfl(sp);
  float o1 = (a1 + eadd1) * inv + bfh(sp);
  if (RELU) { o0 = fmaxf(o0, 0.f); o1 = fmaxf(o1, 0.f); }
  if (OUT_BF16) {
    unsigned int op = ((unsigned int)f2bf(o1) << 16) | (unsigned int)f2bf(o0);
    *(unsigned int*)((unsigned short*)outv + (size_t)node * 128 + c0) = op;
  } else {
    *(float2*)((float*)outv + (size_t)node * 128 + c0) = make_float2(o0, o1);
  }
}

// ---------------------------------------------------------------------------
extern "C" void kernel_launch(void* const* d_in, const int* in_sizes, int n_in,
                              void* d_out, int out_size, void* d_ws, size_t ws_size,
                              hipStream_t stream) {
  const float* x   = (const float*)d_in[0];
  const int*   ei  = (const int*)d_in[1];
  const float* ea  = (const float*)d_in[2];
  const float* Wq0 = (const float*)d_in[3];
  const float* bq0 = (const float*)d_in[4];
  const float* Wk0 = (const float*)d_in[5];
  const float* bk0 = (const float*)d_in[6];
  const float* Wv0 = (const float*)d_in[7];
  const float* bv0 = (const float*)d_in[8];
  const float* We0 = (const float*)d_in[9];
  const float* Ws0 = (const float*)d_in[10];
  const float* bs0 = (const float*)d_in[11];
  const float* Wq1 = (const float*)d_in[12];
  const float* bq1 = (const float*)d_in[13];
  const float* Wk1 = (const float*)d_in[14];
  const float* bk1 = (const float*)d_in[15];
  const float* Wv1 = (const float*)d_in[16];
  const float* bv1 = (const float*)d_in[17];
  const float* We1 = (const float*)d_in[18];
  const float* Ws1 = (const float*)d_in[19];
  const float* bs1 = (const float*)d_in[20];

  char* ws = (char*)d_ws;
  size_t off = 0;
  auto alloc = [&](size_t bytes) -> void* {
    void* p = ws + off;
    off = (off + bytes + 255) & ~(size_t)255;
    return p;
  };
  unsigned short* WT  = (unsigned short*)alloc(8 * 16384 * 2);             // 256 KB
  unsigned short* q   = (unsigned short*)alloc((size_t)N_NODES * 128 * 2); // 12.8 MB
  unsigned short* kvb = (unsigned short*)alloc((size_t)N_NODES * 256 * 2); // 25.6 MB
  unsigned short* s   = (unsigned short*)alloc((size_t)N_NODES * 128 * 2); // 12.8 MB
  unsigned short* h   = (unsigned short*)alloc((size_t)N_NODES * 128 * 2); // 12.8 MB
  int* cnt    = (int*)alloc(N_NODES * 4);
  int* rs     = (int*)alloc((N_NODES + 1) * 4);
  int* cursor = (int*)alloc(N_NODES * 4);
  int2* eidx2 = (int2*)alloc(((size_t)N_EDGES + 8) * 8);                   // 6.4 MB
  // total ~71.3 MB (proven-safe: round 2 ran with ~122 MB)

  const int* srcp = ei;
  const int* dstp = ei + N_EDGES;

  Ptr8 p8 = {{Wq0, Wk0, Wv0, Ws0, Wq1, Wk1, Wv1, Ws1}};
  transpose_w<<<8, 256, 0, stream>>>(p8, WT);
  zero_kernel<<<196, 256, 0, stream>>>(cnt, cursor, (int*)(eidx2 + N_EDGES));
  hist_kernel<<<3125, 256, 0, stream>>>(dstp, cnt);
  scan_kernel<<<1, 1024, 0, stream>>>(cnt, rs);
  scatter_kernel<<<3125, 256, 0, stream>>>(srcp, dstp, rs, cursor, eidx2);

  // layer 0
  GemmArgs ga0 = { x, nullptr, WT, bq0, bk0, bv0, bs0, q, kvb, s, N_NODES };
  node_gemm<true><<<dim3(391, 4), 256, 0, stream>>>(ga0);
  edge_attn<8, true, true><<<12500, 256, 0, stream>>>(q, (const uint2*)kvb, s, We0,
                                                      ea, eidx2, rs, h, 0.25f);

  // layer 1
  GemmArgs ga1 = { nullptr, h, WT + 4 * 16384, bq1, bk1, bv1, bs1, q, kvb, s, N_NODES };
  node_gemm<false><<<dim3(391, 4), 256, 0, stream>>>(ga1);
  edge_attn<64, false, false><<<12500, 256, 0, stream>>>(q, (const uint2*)kvb, s, We1,
                                                         ea, eidx2, rs, d_out, 0.08838834764831845f);
}

// Round 6
// 639.019 us; speedup vs baseline: 1.3456x; 1.0529x over previous
//
#include <hip/hip_runtime.h>
#include <stdint.h>

#define N_NODES 50000
#define N_EDGES 800000

typedef __bf16 bf16x8 __attribute__((ext_vector_type(8)));
typedef float f32x4 __attribute__((ext_vector_type(4)));

__device__ __forceinline__ unsigned short f2bf(float f) {
  union { float f; unsigned int i; } x; x.f = f;
  unsigned int i = x.i;
  unsigned int r = (i + 0x7fffu + ((i >> 16) & 1u)) >> 16;  // round-nearest-even
  return (unsigned short)r;
}
__device__ __forceinline__ float bfl(unsigned int p) {
  union { unsigned int i; float f; } x; x.i = p << 16; return x.f;
}
__device__ __forceinline__ float bfh(unsigned int p) {
  union { unsigned int i; float f; } x; x.i = p & 0xffff0000u; return x.f;
}

// ---------------------------------------------------------------------------
// Weight transpose+convert: W f32 [k=128][n=128] -> Wt bf16 [n][k].
// ---------------------------------------------------------------------------
struct Ptr8 { const float* p[8]; };

__global__ __launch_bounds__(256) void transpose_w(Ptr8 ws, unsigned short* wt) {
  int mat = blockIdx.x;
  const float* W = ws.p[mat];
  unsigned short* out = wt + mat * 16384;
  for (int it = 0; it < 64; ++it) {
    int idx = it * 256 + threadIdx.x;
    int n = idx >> 7, k = idx & 127;
    out[n * 128 + k] = f2bf(W[k * 128 + n]);
  }
}

// ---------------------------------------------------------------------------
// CSR build
// ---------------------------------------------------------------------------
__global__ void zero_kernel(int* cnt, int* cursor, int* srcpad, unsigned int* eapad) {
  int i = blockIdx.x * blockDim.x + threadIdx.x;
  if (i < N_NODES) { cnt[i] = 0; cursor[i] = 0; }
  if (i < 8)  srcpad[i] = 0;   // 8 pad ints after srcArr -> node 0
  if (i < 64) eapad[i] = 0;    // 8 pad rows (16 bf16 each) after eacsr
}

__global__ void hist_kernel(const int* __restrict__ dst, int* __restrict__ cnt) {
  int e = blockIdx.x * blockDim.x + threadIdx.x;
  if (e < N_EDGES) atomicAdd(&cnt[dst[e]], 1);
}

__global__ __launch_bounds__(1024) void scan_kernel(const int* __restrict__ cnt, int* __restrict__ rs) {
  const int n = N_NODES, per = 49;
  int t = threadIdx.x;
  int lo = t * per; int hi = lo + per;
  if (lo > n) lo = n;
  if (hi > n) hi = n;
  int s = 0;
  for (int i = lo; i < hi; ++i) s += cnt[i];
  int lane = t & 63, wv = t >> 6;
  int v = s;
  #pragma unroll
  for (int off = 1; off < 64; off <<= 1) {
    int u = __shfl_up(v, off, 64);
    if (lane >= off) v += u;
  }
  __shared__ int wsum[16], woff[16];
  if (lane == 63) wsum[wv] = v;
  __syncthreads();
  if (t == 0) { int a = 0; for (int w = 0; w < 16; ++w) { woff[w] = a; a += wsum[w]; } }
  __syncthreads();
  int run = woff[wv] + (v - s);
  if (t == 0) rs[0] = 0;
  for (int i = lo; i < hi; ++i) { run += cnt[i]; rs[i + 1] = run; }
}

__global__ void scatter_kernel(const int* __restrict__ src, const int* __restrict__ dst,
                               const int* __restrict__ rs, int* __restrict__ cursor,
                               int* __restrict__ srcArr, int* __restrict__ eidxArr) {
  int e = blockIdx.x * blockDim.x + threadIdx.x;
  if (e < N_EDGES) {
    int d = dst[e];
    int pos = rs[d] + atomicAdd(&cursor[d], 1);
    srcArr[pos]  = src[e];
    eidxArr[pos] = e;
  }
}

// ---------------------------------------------------------------------------
// Gather edge_attr into CSR order, f32 -> bf16: eacsr[r][16] = EA[eidxArr[r]].
// 8 threads per row (float2 each), 32 rows per block.
// ---------------------------------------------------------------------------
__global__ __launch_bounds__(256) void ea_gather(const float* __restrict__ EA,
                                                 const int* __restrict__ eidxArr,
                                                 unsigned short* __restrict__ eacsr) {
  int r = blockIdx.x * 32 + (threadIdx.x >> 3);
  if (r >= N_EDGES) return;
  int j = (threadIdx.x & 7) * 2;
  int e = eidxArr[r];
  float2 v = *(const float2*)(EA + (size_t)e * 16 + j);
  unsigned int pk = (unsigned int)f2bf(v.x) | ((unsigned int)f2bf(v.y) << 16);
  *(unsigned int*)(eacsr + (size_t)r * 16 + j) = pk;
}

// ---------------------------------------------------------------------------
// Merged node GEMM: {q,k,v,s} = X @ {Wq,Wk,Wv,Ws} + b in ONE dispatch.
// X staged to LDS once; weight tile restaged per matrix. Coalesced bf16 out.
// ---------------------------------------------------------------------------
struct Gemm4Args {
  const float* Xf;              // layer-0 input (f32) or null
  const unsigned short* Xh;     // layer-1 input (bf16) or null
  const unsigned short* Wt;     // 4 transposed bf16 mats packed [n][k]
  const float* b[4];
  unsigned short* o[4];         // q, k, v, s
  int M;
};

template<bool XF32>
__global__ __launch_bounds__(256) void node_gemm4(Gemm4Args ga) {
  __shared__ alignas(16) unsigned short At[128 * 128];
  __shared__ alignas(16) unsigned short Bt[128 * 128];
  int m0 = blockIdx.x * 128;
  int lane = threadIdx.x & 63, wv = threadIdx.x >> 6;
  int wm = wv >> 1, wn = wv & 1;
  int lr = lane & 15, lk = lane >> 4;

  // stage A (X tile) once
  #pragma unroll
  for (int it = 0; it < 8; ++it) {
    int c = it * 256 + threadIdx.x;
    int row = c >> 4, slot = c & 15;
    int dsl = slot ^ (row & 7);
    int grow = m0 + row; if (grow >= ga.M) grow = ga.M - 1;
    alignas(16) unsigned short tmp[8];
    if (XF32) {
      const float* xp = ga.Xf + (size_t)grow * 128 + slot * 8;
      float4 a = *(const float4*)xp;
      float4 b = *(const float4*)(xp + 4);
      tmp[0] = f2bf(a.x); tmp[1] = f2bf(a.y); tmp[2] = f2bf(a.z); tmp[3] = f2bf(a.w);
      tmp[4] = f2bf(b.x); tmp[5] = f2bf(b.y); tmp[6] = f2bf(b.z); tmp[7] = f2bf(b.w);
    } else {
      *(uint4*)tmp = *(const uint4*)(ga.Xh + (size_t)grow * 128 + slot * 8);
    }
    *(uint4*)(&At[row * 128 + dsl * 8]) = *(const uint4*)tmp;
  }

  #pragma unroll
  for (int which = 0; which < 4; ++which) {
    if (which) __syncthreads();           // prior MFMA reads of Bt complete
    const unsigned short* Wt = ga.Wt + which * 16384;
    #pragma unroll
    for (int it = 0; it < 8; ++it) {
      int c = it * 256 + threadIdx.x;
      int row = c >> 4, slot = c & 15;
      int dsl = slot ^ (row & 7);
      *(uint4*)(&Bt[row * 128 + dsl * 8]) = *(const uint4*)(Wt + c * 8);
    }
    __syncthreads();

    f32x4 acc[4][4];
    #pragma unroll
    for (int mi = 0; mi < 4; ++mi)
      #pragma unroll
      for (int ni = 0; ni < 4; ++ni) acc[mi][ni] = (f32x4){0.f, 0.f, 0.f, 0.f};

    #pragma unroll
    for (int kk = 0; kk < 4; ++kk) {
      bf16x8 af[4], bfr[4];
      #pragma unroll
      for (int mi = 0; mi < 4; ++mi) {
        int row = wm * 64 + mi * 16 + lr;
        int slot = (kk * 4 + lk) ^ (row & 7);
        af[mi] = *(const bf16x8*)(&At[row * 128 + slot * 8]);
      }
      #pragma unroll
      for (int ni = 0; ni < 4; ++ni) {
        int row = wn * 64 + ni * 16 + lr;
        int slot = (kk * 4 + lk) ^ (row & 7);
        bfr[ni] = *(const bf16x8*)(&Bt[row * 128 + slot * 8]);
      }
      #pragma unroll
      for (int mi = 0; mi < 4; ++mi)
        #pragma unroll
        for (int ni = 0; ni < 4; ++ni)
          acc[mi][ni] = __builtin_amdgcn_mfma_f32_16x16x32_bf16(af[mi], bfr[ni], acc[mi][ni], 0, 0, 0);
    }

    const float* bias = ga.b[which];
    unsigned short* outp = ga.o[which];
    float bv[4];
    #pragma unroll
    for (int ni = 0; ni < 4; ++ni) bv[ni] = bias[wn * 64 + ni * 16 + lr];
    #pragma unroll
    for (int mi = 0; mi < 4; ++mi) {
      #pragma unroll
      for (int i = 0; i < 4; ++i) {
        int row = m0 + wm * 64 + mi * 16 + lk * 4 + i;
        if (row < ga.M) {
          #pragma unroll
          for (int ni = 0; ni < 4; ++ni) {
            int col = wn * 64 + ni * 16 + lr;
            outp[(size_t)row * 128 + col] = f2bf(acc[mi][ni][i] + bv[ni]);
          }
        }
      }
    }
  }
}

// ---------------------------------------------------------------------------
// Per-dst-node fused attention v4: factored edge-MLP, bf16 CSR-streamed ea,
// split k/v gathers, 8-edge chunks, 3-stage pipeline, static double buffers.
// ---------------------------------------------------------------------------
template<int CHALF, bool RELU, bool OUT_BF16>
__global__ __launch_bounds__(256) void edge_attn(
    const unsigned short* __restrict__ Q, const unsigned short* __restrict__ Kb,
    const unsigned short* __restrict__ Vb, const unsigned short* __restrict__ S,
    const float* __restrict__ We, const unsigned short* __restrict__ EAC,
    const int* __restrict__ srcArr, const int* __restrict__ rs,
    void* __restrict__ outv, float inv_sqrt_c) {
  int wv = threadIdx.x >> 6, lane = threadIdx.x & 63;
  int node = blockIdx.x * 4 + wv;
  if (node >= N_NODES) return;
  int c0 = lane * 2;
  int jbase = (lane & 1) * 8 + ((lane >> 1) & 1) * 4 + ((lane >> 2) & 1) * 2;

  unsigned int qp = *(const unsigned int*)(Q + (size_t)node * 128 + c0);
  unsigned int sp = *(const unsigned int*)(S + (size_t)node * 128 + c0);  // hoisted skip
  float qa = bfl(qp) * inv_sqrt_c;
  float qb = bfh(qp) * inv_sqrt_c;

  // ---- qWe[j] = sum_c q[c]*We[j][c], reduce-scattered over lane bits 0..2 ----
  float part[16];
  #pragma unroll
  for (int j = 0; j < 16; ++j) {
    float2 wp = *(const float2*)(We + j * 128 + c0);
    part[j] = qa * wp.x + qb * wp.y;
  }
  {
    bool hi = lane & 1;
    #pragma unroll
    for (int j = 0; j < 8; ++j) {
      float kept = hi ? part[j + 8] : part[j];
      float sent = hi ? part[j] : part[j + 8];
      part[j] = kept + __shfl_xor(sent, 1, 64);
    }
    hi = lane & 2;
    #pragma unroll
    for (int j = 0; j < 4; ++j) {
      float kept = hi ? part[j + 4] : part[j];
      float sent = hi ? part[j] : part[j + 4];
      part[j] = kept + __shfl_xor(sent, 2, 64);
    }
    hi = lane & 4;
    #pragma unroll
    for (int j = 0; j < 2; ++j) {
      float kept = hi ? part[j + 2] : part[j];
      float sent = hi ? part[j] : part[j + 2];
      part[j] = kept + __shfl_xor(sent, 4, 64);
    }
  }
  if (CHALF == 64) {
    #pragma unroll
    for (int s = 8; s <= 32; s <<= 1) {
      part[0] += __shfl_xor(part[0], s, 64);
      part[1] += __shfl_xor(part[1], s, 64);
    }
  }
  float qw0 = part[0] * (CHALF == 64 ? 0.125f : 1.0f);
  float qw1 = part[1] * (CHALF == 64 ? 0.125f : 1.0f);

  int i0 = rs[node], i1 = rs[node + 1];
  int deg = i1 - i0;
  float den = 0.f, a0 = 0.f, a1 = 0.f, wea0 = 0.f, wea1 = 0.f;

  struct Buf { unsigned int kp[8], vp[8], ep[8]; };
  Buf bA, bB;
  int svA = 0, svB = 0;

  auto load_src = [&](int c) -> int {
    return srcArr[i0 + c * 8 + (lane & 7)];
  };
  auto gather = [&](Buf& b, int c, int sv) {
    #pragma unroll
    for (int j = 0; j < 8; ++j) {
      int s = __shfl(sv, j, 8);
      b.kp[j] = *(const unsigned int*)(Kb + (size_t)s * 128 + c0);
      b.vp[j] = *(const unsigned int*)(Vb + (size_t)s * 128 + c0);
      b.ep[j] = *(const unsigned int*)(EAC + (size_t)(i0 + c * 8 + j) * 16 + jbase);
    }
  };
  auto compute = [&](const Buf& b, int c) {
    #pragma unroll
    for (int j = 0; j < 8; ++j) {
      int g = i0 + c * 8 + j;
      float ea0 = bfl(b.ep[j]), ea1 = bfh(b.ep[j]);
      float p = qa * bfl(b.kp[j]) + qb * bfh(b.kp[j]) + qw0 * ea0 + qw1 * ea1;
      #pragma unroll
      for (int off = 1; off < CHALF; off <<= 1) p += __shfl_xor(p, off, 64);
      float w = (g < i1) ? __expf(p) : 0.f;
      den  += w;
      a0   += w * bfl(b.vp[j]);
      a1   += w * bfh(b.vp[j]);
      wea0 += w * ea0;
      wea1 += w * ea1;
    }
  };

  int nch = (deg + 7) >> 3;
  if (nch > 0) {
    svA = load_src(0);
    if (nch > 1) svB = load_src(1);
    gather(bA, 0, svA);
    int c = 0;
    while (true) {
      if (c + 1 < nch) gather(bB, c + 1, svB);
      if (c + 2 < nch) svA = load_src(c + 2);
      compute(bA, c);
      ++c; if (c >= nch) break;
      if (c + 1 < nch) gather(bA, c + 1, svA);
      if (c + 2 < nch) svB = load_src(c + 2);
      compute(bB, c);
      ++c; if (c >= nch) break;
    }
  }

  // ---- epilogue: (a + wea@We)/den + skip ----
  float inv = 1.f / (den + 1e-16f);
  float eadd0 = 0.f, eadd1 = 0.f;
  #pragma unroll
  for (int j = 0; j < 16; ++j) {
    int owner = ((j >> 3) & 1) | (((j >> 2) & 1) << 1) | (((j >> 1) & 1) << 2);
    int srcl = (lane & 56) | owner;
    float val = __shfl((j & 1) ? wea1 : wea0, srcl, 64);
    float2 wp = *(const float2*)(We + j * 128 + c0);
    eadd0 += val * wp.x;
    eadd1 += val * wp.y;
  }
  float o0 = (a0 + eadd0) * inv + bfl(sp);
  float o1 = (a1 + eadd1) * inv + bfh(sp);
  if (RELU) { o0 = fmaxf(o0, 0.f); o1 = fmaxf(o1, 0.f); }
  if (OUT_BF16) {
    unsigned int op = ((unsigned int)f2bf(o1) << 16) | (unsigned int)f2bf(o0);
    *(unsigned int*)((unsigned short*)outv + (size_t)node * 128 + c0) = op;
  } else {
    *(float2*)((float*)outv + (size_t)node * 128 + c0) = make_float2(o0, o1);
  }
}

// ---------------------------------------------------------------------------
extern "C" void kernel_launch(void* const* d_in, const int* in_sizes, int n_in,
                              void* d_out, int out_size, void* d_ws, size_t ws_size,
                              hipStream_t stream) {
  const float* x   = (const float*)d_in[0];
  const int*   ei  = (const int*)d_in[1];
  const float* ea  = (const float*)d_in[2];
  const float* Wq0 = (const float*)d_in[3];
  const float* bq0 = (const float*)d_in[4];
  const float* Wk0 = (const float*)d_in[5];
  const float* bk0 = (const float*)d_in[6];
  const float* Wv0 = (const float*)d_in[7];
  const float* bv0 = (const float*)d_in[8];
  const float* We0 = (const float*)d_in[9];
  const float* Ws0 = (const float*)d_in[10];
  const float* bs0 = (const float*)d_in[11];
  const float* Wq1 = (const float*)d_in[12];
  const float* bq1 = (const float*)d_in[13];
  const float* Wk1 = (const float*)d_in[14];
  const float* bk1 = (const float*)d_in[15];
  const float* Wv1 = (const float*)d_in[16];
  const float* bv1 = (const float*)d_in[17];
  const float* We1 = (const float*)d_in[18];
  const float* Ws1 = (const float*)d_in[19];
  const float* bs1 = (const float*)d_in[20];

  char* ws = (char*)d_ws;
  size_t off = 0;
  auto alloc = [&](size_t bytes) -> void* {
    void* p = ws + off;
    off = (off + bytes + 255) & ~(size_t)255;
    return p;
  };
  unsigned short* WT    = (unsigned short*)alloc(8 * 16384 * 2);             // 256 KB
  unsigned short* q     = (unsigned short*)alloc((size_t)N_NODES * 128 * 2); // 12.8 MB
  unsigned short* k     = (unsigned short*)alloc((size_t)N_NODES * 128 * 2);
  unsigned short* v     = (unsigned short*)alloc((size_t)N_NODES * 128 * 2);
  unsigned short* s     = (unsigned short*)alloc((size_t)N_NODES * 128 * 2);
  unsigned short* h     = (unsigned short*)alloc((size_t)N_NODES * 128 * 2);
  unsigned short* eacsr = (unsigned short*)alloc(((size_t)N_EDGES + 8) * 16 * 2); // 25.6 MB
  int* cnt     = (int*)alloc(N_NODES * 4);
  int* rs      = (int*)alloc((N_NODES + 1) * 4);
  int* cursor  = (int*)alloc(N_NODES * 4);
  int* srcArr  = (int*)alloc(((size_t)N_EDGES + 8) * 4);                     // 3.2 MB
  int* eidxArr = (int*)alloc((size_t)N_EDGES * 4);                           // 3.2 MB
  // total ~97 MB (proven-safe: round 2 ran with ~122 MB)

  const int* srcp = ei;
  const int* dstp = ei + N_EDGES;

  Ptr8 p8 = {{Wq0, Wk0, Wv0, Ws0, Wq1, Wk1, Wv1, Ws1}};
  transpose_w<<<8, 256, 0, stream>>>(p8, WT);
  zero_kernel<<<196, 256, 0, stream>>>(cnt, cursor, srcArr + N_EDGES,
                                       (unsigned int*)(eacsr + (size_t)N_EDGES * 16));
  hist_kernel<<<3125, 256, 0, stream>>>(dstp, cnt);
  scan_kernel<<<1, 1024, 0, stream>>>(cnt, rs);
  scatter_kernel<<<3125, 256, 0, stream>>>(srcp, dstp, rs, cursor, srcArr, eidxArr);
  ea_gather<<<25000, 256, 0, stream>>>(ea, eidxArr, eacsr);

  // layer 0
  Gemm4Args ga0 = { x, nullptr, WT, {bq0, bk0, bv0, bs0}, {q, k, v, s}, N_NODES };
  node_gemm4<true><<<391, 256, 0, stream>>>(ga0);
  edge_attn<8, true, true><<<12500, 256, 0, stream>>>(q, k, v, s, We0, eacsr,
                                                      srcArr, rs, h, 0.25f);

  // layer 1
  Gemm4Args ga1 = { nullptr, h, WT + 4 * 16384, {bq1, bk1, bv1, bs1}, {q, k, v, s}, N_NODES };
  node_gemm4<false><<<391, 256, 0, stream>>>(ga1);
  edge_attn<64, false, false><<<12500, 256, 0, stream>>>(q, k, v, s, We1, eacsr,
                                                         srcArr, rs, d_out, 0.08838834764831845f);
}